// Round 8
// baseline (385.574 us; speedup 1.0000x reference)
//
#include <hip/hip_runtime.h>
#include <math.h>

#define BN_EPS 1e-5f
constexpr int CAP = 64;     // max neighbors/node incl self-loop; deg~Poisson(16), P(>63)~0
constexpr int BSH = 9;      // dst-bucket shift: 512 nodes / bucket
constexpr int BCAP = 10240; // entries per bucket (avg 8192, sd ~90; +22 sigma)

typedef __attribute__((ext_vector_type(8))) short bf16x8;
typedef __attribute__((ext_vector_type(4))) float f32x4;

// ---- bf16 helpers (round-to-nearest-even) ----
__device__ inline unsigned short f2bf(float f) {
    unsigned u = __float_as_uint(f);
    unsigned r = (u + 0x7fffu + ((u >> 16) & 1u)) >> 16;
    return (unsigned short)r;
}
__device__ inline float2 bf2_to_f2(unsigned int v) {
    float2 r;
    r.x = __uint_as_float(v << 16);
    r.y = __uint_as_float(v & 0xffff0000u);
    return r;
}
__device__ inline void addv(float* a, uint4 v) {
    float2 x0 = bf2_to_f2(v.x), x1 = bf2_to_f2(v.y), x2 = bf2_to_f2(v.z), x3 = bf2_to_f2(v.w);
    a[0] += x0.x; a[1] += x0.y; a[2] += x1.x; a[3] += x1.y;
    a[4] += x2.x; a[5] += x2.y; a[6] += x3.x; a[7] += x3.y;
}

// ---------------- graph build: 2-phase dst-binned counting sort ----------------
__global__ __launch_bounds__(256) void k_zero(int* __restrict__ buf, int L) {
    int i = blockIdx.x * 256 + threadIdx.x;
    if (i < L) buf[i] = 0;
}

__global__ __launch_bounds__(256) void k_bin(const int* __restrict__ ei, int E, int K,
                                             uint2* __restrict__ bins, int* __restrict__ bcnt) {
    __shared__ int hist[256];
    __shared__ int lbase[256];
    const int tid = threadIdx.x;
    const int e0 = blockIdx.x * 2048;
    hist[tid] = 0;
    __syncthreads();

    int s[8], d[8];
    bool m[8];
#pragma unroll
    for (int i = 0; i < 8; ++i) {
        int e = e0 + i * 256 + tid;
        m[i] = e < E;
        s[i] = m[i] ? ei[e] : 0;
        d[i] = m[i] ? ei[E + e] : 0;
        if (m[i]) atomicAdd(&hist[d[i] >> BSH], 1);
    }
    __syncthreads();
    if (tid < K && hist[tid] > 0) lbase[tid] = atomicAdd(&bcnt[tid], hist[tid]);
    __syncthreads();
    hist[tid] = 0;
    __syncthreads();
#pragma unroll
    for (int i = 0; i < 8; ++i) {
        if (m[i]) {
            int b = d[i] >> BSH;
            int pos = lbase[b] + atomicAdd(&hist[b], 1);
            if (pos < BCAP) bins[(size_t)b * BCAP + pos] = make_uint2((unsigned)s[i], (unsigned)d[i]);
        }
    }
}

__global__ __launch_bounds__(1024) void k_place(const uint2* __restrict__ bins,
                                                const int* __restrict__ bcnt,
                                                int* __restrict__ col, int* __restrict__ cnt,
                                                float* __restrict__ dinv, int* __restrict__ dhist,
                                                int N) {
    const int b = blockIdx.x;
    const int node0 = b << BSH;
    const int nn = min(1 << BSH, N - node0);
    __shared__ int c2[1 << BSH];
    __shared__ int lh[CAP + 2];
    const int tid = threadIdx.x;
    if (tid < CAP + 2) lh[tid] = 0;
    for (int i = tid; i < nn; i += 1024) {
        c2[i] = 1;
        col[(size_t)(node0 + i) * CAP] = node0 + i;
    }
    __syncthreads();
    const int nb = min(bcnt[b], BCAP);
    const uint2* __restrict__ bb = bins + (size_t)b * BCAP;
    for (int i = tid; i < nb; i += 1024) {
        uint2 e = bb[i];
        int pos = atomicAdd(&c2[(int)e.y - node0], 1);
        if (pos < CAP) col[(size_t)e.y * CAP + pos] = (int)e.x;
    }
    __syncthreads();
    for (int i = tid; i < nn; i += 1024) {
        int c = c2[i];
        cnt[node0 + i] = c;
        dinv[node0 + i] = rsqrtf((float)c);
        atomicAdd(&lh[min(c, CAP)], 1);
    }
    __syncthreads();
    if (tid <= CAP && lh[tid] > 0) atomicAdd(&dhist[tid], lh[tid]);
}

// exclusive prefix over degree histogram -> doff
__global__ void k_prefix(const int* __restrict__ dhist, int* __restrict__ doff) {
    if (threadIdx.x == 0) {
        int s = 0;
        for (int b = 0; b <= CAP; ++b) { doff[b] = s; s += dhist[b]; }
    }
}

// scatter node ids into degree-sorted permutation (k_bin pattern: LDS hist + range reserve)
__global__ __launch_bounds__(256) void k_scatter(const int* __restrict__ cnt, int* __restrict__ doff,
                                                 int* __restrict__ perm, int N) {
    __shared__ int lh[CAP + 2];
    __shared__ int lbase[CAP + 2];
    __shared__ int lpos[CAP + 2];
    const int tid = threadIdx.x;
    if (tid < CAP + 2) { lh[tid] = 0; lpos[tid] = 0; }
    __syncthreads();
    const int i = blockIdx.x * 256 + tid;
    const bool act = i < N;
    int b = 0;
    if (act) { b = min(cnt[i], CAP); atomicAdd(&lh[b], 1); }
    __syncthreads();
    if (tid <= CAP && lh[tid] > 0) lbase[tid] = atomicAdd(&doff[tid], lh[tid]);
    __syncthreads();
    if (act) {
        int p = atomicAdd(&lpos[b], 1);
        perm[lbase[b] + p] = i;
    }
}

// ---------------- weight repack: fp32 [FIN][FOUT] -> bf16 fragment-linear ----------------
__global__ __launch_bounds__(256) void k_repack(
    const float* __restrict__ w_in, const float* __restrict__ w1,
    const float* __restrict__ w2, const float* __restrict__ w3,
    unsigned short* __restrict__ f_in, unsigned short* __restrict__ f1,
    unsigned short* __restrict__ f2, unsigned short* __restrict__ f3)
{
    int idx = blockIdx.x * 256 + threadIdx.x;  // 0..40959
    const float* src;
    unsigned short* dst;
    int FOUT, local;
    if (idx < 8192)       { src = w_in; dst = f_in; FOUT = 64;  local = idx; }
    else if (idx < 16384) { src = w1;   dst = f1;   FOUT = 128; local = idx - 8192; }
    else if (idx < 32768) { src = w2;   dst = f2;   FOUT = 128; local = idx - 16384; }
    else                  { src = w3;   dst = f3;   FOUT = 64;  local = idx - 32768; }
    int k = local / FOUT, n = local % FOUT;
    int NT = FOUT >> 4;
    dst[((((k >> 5) * NT + (n >> 4)) * 64) + ((k >> 3) & 3) * 16 + (n & 15)) * 8 + (k & 7)] = f2bf(src[local]);
}

// ---------------- layer 0: h0 = bf16( dinv * relu(x @ w_in + b_in) ) ----------------
__global__ __launch_bounds__(256) void mfma_gemm0(
    const float* __restrict__ in, const unsigned short* __restrict__ wfrag,
    const float* __restrict__ bias, const float* __restrict__ rowscale,
    unsigned short* __restrict__ out, int N)
{
    constexpr int FIN = 128, FOUT = 64, KS = 4, NT = 4, OST = 72;
    __shared__ unsigned short otile[4 * 16 * OST];
    __shared__ float ct[FOUT];
    const int tid = threadIdx.x;
    if (tid < FOUT) ct[tid] = bias[tid];
    __syncthreads();

    const int wid = tid >> 6, lane = tid & 63;
    const int q = lane >> 4, m = lane & 15;
    const int rowbase = blockIdx.x * 64 + wid * 16;
    const int rowc = min(rowbase + m, N - 1);
    const bf16x8* __restrict__ wf = (const bf16x8*)wfrag;

    f32x4 accm[NT];
#pragma unroll
    for (int nt = 0; nt < NT; ++nt) accm[nt] = (f32x4){0.f, 0.f, 0.f, 0.f};

#pragma unroll
    for (int ks = 0; ks < KS; ++ks) {
        const float* ap = in + (size_t)rowc * FIN + ks * 32 + q * 8;
        float4 a0 = *(const float4*)ap;
        float4 a1 = *(const float4*)(ap + 4);
        bf16x8 af;
        af[0] = (short)f2bf(a0.x); af[1] = (short)f2bf(a0.y);
        af[2] = (short)f2bf(a0.z); af[3] = (short)f2bf(a0.w);
        af[4] = (short)f2bf(a1.x); af[5] = (short)f2bf(a1.y);
        af[6] = (short)f2bf(a1.z); af[7] = (short)f2bf(a1.w);
#pragma unroll
        for (int nt = 0; nt < NT; ++nt)
            accm[nt] = __builtin_amdgcn_mfma_f32_16x16x32_bf16(af, wf[(ks * NT + nt) * 64 + lane], accm[nt], 0, 0, 0);
    }

    unsigned short* ot = otile + wid * 16 * OST;
    float rs[4];
#pragma unroll
    for (int r = 0; r < 4; ++r) rs[r] = rowscale[min(rowbase + q * 4 + r, N - 1)];
#pragma unroll
    for (int nt = 0; nt < NT; ++nt) {
        int c = nt * 16 + m;
        float t = ct[c];
#pragma unroll
        for (int r = 0; r < 4; ++r) {
            float z = fmaxf(accm[nt][r] + t, 0.f);
            ot[(q * 4 + r) * OST + c] = f2bf(z * rs[r]);
        }
    }
#pragma unroll
    for (int idx = lane; idx < 16 * (FOUT / 8); idx += 64) {
        int rrow = idx >> 3, cc = idx & 7;
        int gr = rowbase + rrow;
        if (gr < N)
            *(uint4*)(out + (size_t)gr * FOUT + cc * 8) = *(const uint4*)&ot[rrow * OST + cc * 8];
    }
}

// ---------------- layer 1: h1 = bf16( dinv * relu(bn1( (A_hat@h0) @ w1 + b1 )) ) ----------------
// Gather-in-fragment, degree-equalized: wave's 16 nodes come from perm (sorted by degree).
__global__ __launch_bounds__(256) void agg_mfma1(
    const unsigned short* __restrict__ hin, const unsigned short* __restrict__ wfrag,
    const float* __restrict__ bias, const float* __restrict__ g, const float* __restrict__ beta,
    const float* __restrict__ mm, const float* __restrict__ vv,
    const int* __restrict__ col, const int* __restrict__ cnt, const float* __restrict__ dinv,
    const int* __restrict__ perm,
    unsigned short* __restrict__ out, int N)
{
    constexpr int FIN = 64, FOUT = 128, KS = 2, NT = 8, OST = 136;
    __shared__ unsigned short otile[4 * 16 * OST];
    __shared__ float cs[FOUT], ct[FOUT];
    __shared__ int lperm[64];
    const int tid = threadIdx.x;
    if (tid < FOUT) {
        float s = g[tid] * rsqrtf(vv[tid] + BN_EPS);
        cs[tid] = s;
        ct[tid] = bias[tid] * s + beta[tid] - mm[tid] * s;
    }
    if (tid < 64) lperm[tid] = perm[min((int)(blockIdx.x * 64 + tid), N - 1)];
    __syncthreads();

    const int wid = tid >> 6, lane = tid & 63;
    const int q = lane >> 4, m = lane & 15;
    const int rowbase = blockIdx.x * 64 + wid * 16;
    const int node = lperm[wid * 16 + m];
    const int n = (rowbase + m < N) ? min(cnt[node], CAP) : 0;
    const int* __restrict__ c = col + (size_t)node * CAP;

    float acc[KS][8];
#pragma unroll
    for (int i = 0; i < KS; ++i)
#pragma unroll
        for (int e = 0; e < 8; ++e) acc[i][e] = 0.f;

    int p = 0;
    for (; p + 2 <= n; p += 2) {
        const unsigned short* r0 = hin + (size_t)c[p] * FIN + q * 8;
        const unsigned short* r1 = hin + (size_t)c[p + 1] * FIN + q * 8;
        uint4 v00 = *(const uint4*)r0, v01 = *(const uint4*)(r0 + 32);
        uint4 v10 = *(const uint4*)r1, v11 = *(const uint4*)(r1 + 32);
        addv(acc[0], v00); addv(acc[1], v01);
        addv(acc[0], v10); addv(acc[1], v11);
    }
    if (p < n) {
        const unsigned short* r0 = hin + (size_t)c[p] * FIN + q * 8;
        addv(acc[0], *(const uint4*)r0);
        addv(acc[1], *(const uint4*)(r0 + 32));
    }

    const float di = dinv[node];
    bf16x8 af[KS];
#pragma unroll
    for (int i = 0; i < KS; ++i)
#pragma unroll
        for (int e = 0; e < 8; ++e) af[i][e] = (short)f2bf(acc[i][e] * di);

    f32x4 accm[NT];
#pragma unroll
    for (int nt = 0; nt < NT; ++nt) accm[nt] = (f32x4){0.f, 0.f, 0.f, 0.f};
    const bf16x8* __restrict__ wf = (const bf16x8*)wfrag;
#pragma unroll
    for (int ks = 0; ks < KS; ++ks)
#pragma unroll
        for (int nt = 0; nt < NT; ++nt)
            accm[nt] = __builtin_amdgcn_mfma_f32_16x16x32_bf16(af[ks], wf[(ks * NT + nt) * 64 + lane], accm[nt], 0, 0, 0);

    unsigned short* ot = otile + wid * 16 * OST;
    float rs[4];
#pragma unroll
    for (int r = 0; r < 4; ++r) rs[r] = dinv[lperm[wid * 16 + q * 4 + r]];
#pragma unroll
    for (int nt = 0; nt < NT; ++nt) {
        int cc = nt * 16 + m;
        float s = cs[cc], t = ct[cc];
#pragma unroll
        for (int r = 0; r < 4; ++r) {
            float z = fmaxf(accm[nt][r] * s + t, 0.f);
            ot[(q * 4 + r) * OST + cc] = f2bf(z * rs[r]);
        }
    }
#pragma unroll
    for (int idx = lane; idx < 16 * (FOUT / 8); idx += 64) {
        int rrow = idx >> 4, cc = idx & 15;
        if (rowbase + rrow < N) {
            int gr = lperm[wid * 16 + rrow];
            *(uint4*)(out + (size_t)gr * FOUT + cc * 8) = *(const uint4*)&ot[rrow * OST + cc * 8];
        }
    }
}

// ---------------- layers 2+3 fused: t3 = bf16( dinv * ( relu(bn2((A_hat@h1)@w2+b2)) @ w3 ) ) ----------------
__global__ __launch_bounds__(256) void agg_mfma23(
    const unsigned short* __restrict__ hin, const unsigned short* __restrict__ w2f,
    const float* __restrict__ b2, const float* __restrict__ g2, const float* __restrict__ beta2,
    const float* __restrict__ m2, const float* __restrict__ v2,
    const unsigned short* __restrict__ w3f,
    const int* __restrict__ col, const int* __restrict__ cnt, const float* __restrict__ dinv,
    const int* __restrict__ perm,
    unsigned short* __restrict__ out, int N)
{
    constexpr int FIN = 128, KS = 4, NT1 = 8, NT2 = 4, OST = 136, OST2 = 72;
    __shared__ unsigned short otile[4 * 16 * OST];
    __shared__ float cs[128], ct[128];
    __shared__ int lperm[64];
    const int tid = threadIdx.x;
    if (tid < 128) {
        float s = g2[tid] * rsqrtf(v2[tid] + BN_EPS);
        cs[tid] = s;
        ct[tid] = b2[tid] * s + beta2[tid] - m2[tid] * s;
    }
    if (tid < 64) lperm[tid] = perm[min((int)(blockIdx.x * 64 + tid), N - 1)];
    __syncthreads();

    const int wid = tid >> 6, lane = tid & 63;
    const int q = lane >> 4, m = lane & 15;
    const int rowbase = blockIdx.x * 64 + wid * 16;
    const int node = lperm[wid * 16 + m];
    const int n = (rowbase + m < N) ? min(cnt[node], CAP) : 0;
    const int* __restrict__ c = col + (size_t)node * CAP;

    float acc[KS][8];
#pragma unroll
    for (int i = 0; i < KS; ++i)
#pragma unroll
        for (int e = 0; e < 8; ++e) acc[i][e] = 0.f;

    int p = 0;
    for (; p + 2 <= n; p += 2) {
        const unsigned short* r0 = hin + (size_t)c[p] * FIN + q * 8;
        const unsigned short* r1 = hin + (size_t)c[p + 1] * FIN + q * 8;
#pragma unroll
        for (int i = 0; i < KS; ++i) addv(acc[i], *(const uint4*)(r0 + i * 32));
#pragma unroll
        for (int i = 0; i < KS; ++i) addv(acc[i], *(const uint4*)(r1 + i * 32));
    }
    if (p < n) {
        const unsigned short* r0 = hin + (size_t)c[p] * FIN + q * 8;
#pragma unroll
        for (int i = 0; i < KS; ++i) addv(acc[i], *(const uint4*)(r0 + i * 32));
    }

    const float di = dinv[node];
    bf16x8 af[KS];
#pragma unroll
    for (int i = 0; i < KS; ++i)
#pragma unroll
        for (int e = 0; e < 8; ++e) af[i][e] = (short)f2bf(acc[i][e] * di);

    // MFMA1: z2 = a2 @ w2
    f32x4 accm[NT1];
#pragma unroll
    for (int nt = 0; nt < NT1; ++nt) accm[nt] = (f32x4){0.f, 0.f, 0.f, 0.f};
    const bf16x8* __restrict__ wf2 = (const bf16x8*)w2f;
#pragma unroll
    for (int ks = 0; ks < KS; ++ks)
#pragma unroll
        for (int nt = 0; nt < NT1; ++nt)
            accm[nt] = __builtin_amdgcn_mfma_f32_16x16x32_bf16(af[ks], wf2[(ks * NT1 + nt) * 64 + lane], accm[nt], 0, 0, 0);

    // h2 = relu(bn2(z2)) -> per-wave LDS tile (C-layout rows -> A-frag reads)
    unsigned short* ot = otile + wid * 16 * OST;
#pragma unroll
    for (int nt = 0; nt < NT1; ++nt) {
        int cc = nt * 16 + m;
        float s = cs[cc], t = ct[cc];
#pragma unroll
        for (int r = 0; r < 4; ++r) {
            float z = fmaxf(accm[nt][r] * s + t, 0.f);
            ot[(q * 4 + r) * OST + cc] = f2bf(z);
        }
    }
    bf16x8 af2[KS];
#pragma unroll
    for (int ks = 0; ks < KS; ++ks)
        af2[ks] = *(const bf16x8*)&ot[m * OST + ks * 32 + q * 8];

    // MFMA2: t3 = h2 @ w3
    f32x4 acc2[NT2];
#pragma unroll
    for (int nt = 0; nt < NT2; ++nt) acc2[nt] = (f32x4){0.f, 0.f, 0.f, 0.f};
    const bf16x8* __restrict__ wf3 = (const bf16x8*)w3f;
#pragma unroll
    for (int ks = 0; ks < KS; ++ks)
#pragma unroll
        for (int nt = 0; nt < NT2; ++nt)
            acc2[nt] = __builtin_amdgcn_mfma_f32_16x16x32_bf16(af2[ks], wf3[(ks * NT2 + nt) * 64 + lane], acc2[nt], 0, 0, 0);

    float rs[4];
#pragma unroll
    for (int r = 0; r < 4; ++r) rs[r] = dinv[lperm[wid * 16 + q * 4 + r]];
#pragma unroll
    for (int nt = 0; nt < NT2; ++nt) {
        int cc = nt * 16 + m;
#pragma unroll
        for (int r = 0; r < 4; ++r)
            ot[(q * 4 + r) * OST2 + cc] = f2bf(acc2[nt][r] * rs[r]);
    }
#pragma unroll
    for (int idx = lane; idx < 16 * 8; idx += 64) {
        int rrow = idx >> 3, cc = idx & 7;
        if (rowbase + rrow < N) {
            int gr = lperm[wid * 16 + rrow];
            *(uint4*)(out + (size_t)gr * 64 + cc * 8) = *(const uint4*)&ot[rrow * OST2 + cc * 8];
        }
    }
}

// ---------------- layer 3 tail fused: out = log_softmax( relu(bn3(A_hat@t3 + b3)) @ w_out + b_out ) ----------------
__global__ __launch_bounds__(256) void agg_final(
    const unsigned short* __restrict__ hin,
    const int* __restrict__ col, const int* __restrict__ cnt, const float* __restrict__ dinv,
    const int* __restrict__ perm,
    const float* __restrict__ b3, const float* __restrict__ g3, const float* __restrict__ beta3,
    const float* __restrict__ m3, const float* __restrict__ v3,
    const float* __restrict__ w_out, const float* __restrict__ b_out,
    float* __restrict__ out, int N)
{
    __shared__ float S[64], T[64], sw[64 * 8], sb[8];
    __shared__ int lperm[64];
    const int tid = threadIdx.x;
    if (tid < 64) {
        float s = g3[tid] * rsqrtf(v3[tid] + BN_EPS);
        S[tid] = s;
        T[tid] = b3[tid] * s + beta3[tid] - m3[tid] * s;
        lperm[tid] = perm[min((int)(blockIdx.x * 64 + tid), N - 1)];
    }
    if (tid < 8) sb[tid] = b_out[tid];
    sw[tid] = w_out[tid];
    sw[tid + 256] = w_out[tid + 256];
    __syncthreads();

    const int wid = tid >> 6, lane = tid & 63;
    const int q = lane >> 4, m = lane & 15;
    const int rowbase = blockIdx.x * 64 + wid * 16;
    const int node = lperm[wid * 16 + m];
    const int n = (rowbase + m < N) ? min(cnt[node], CAP) : 0;
    const int* __restrict__ c = col + (size_t)node * CAP;

    float acc[2][8];
#pragma unroll
    for (int i = 0; i < 2; ++i)
#pragma unroll
        for (int e = 0; e < 8; ++e) acc[i][e] = 0.f;

    int p = 0;
    for (; p + 2 <= n; p += 2) {
        const unsigned short* r0 = hin + (size_t)c[p] * 64 + q * 8;
        const unsigned short* r1 = hin + (size_t)c[p + 1] * 64 + q * 8;
        addv(acc[0], *(const uint4*)r0); addv(acc[1], *(const uint4*)(r0 + 32));
        addv(acc[0], *(const uint4*)r1); addv(acc[1], *(const uint4*)(r1 + 32));
    }
    if (p < n) {
        const unsigned short* r0 = hin + (size_t)c[p] * 64 + q * 8;
        addv(acc[0], *(const uint4*)r0);
        addv(acc[1], *(const uint4*)(r0 + 32));
    }

    const float di = dinv[node];
    float lg[8];
#pragma unroll
    for (int cc = 0; cc < 8; ++cc) lg[cc] = 0.f;
#pragma unroll
    for (int i = 0; i < 2; ++i) {
        int fbase = i * 32 + q * 8;
#pragma unroll
        for (int j = 0; j < 8; ++j) {
            int f = fbase + j;
            float z = fmaxf((acc[i][j] * di) * S[f] + T[f], 0.f);
#pragma unroll
            for (int cc = 0; cc < 8; ++cc) lg[cc] += z * sw[f * 8 + cc];
        }
    }
#pragma unroll
    for (int cc = 0; cc < 8; ++cc) {
        lg[cc] += __shfl_xor(lg[cc], 16);
        lg[cc] += __shfl_xor(lg[cc], 32);
    }
    if (q == 0 && rowbase + m < N) {
#pragma unroll
        for (int cc = 0; cc < 8; ++cc) lg[cc] += sb[cc];
        float mx = lg[0];
#pragma unroll
        for (int cc = 1; cc < 8; ++cc) mx = fmaxf(mx, lg[cc]);
        float sum = 0.f;
#pragma unroll
        for (int cc = 0; cc < 8; ++cc) sum += expf(lg[cc] - mx);
        float lse = logf(sum) + mx;
        float4 o0 = {lg[0] - lse, lg[1] - lse, lg[2] - lse, lg[3] - lse};
        float4 o1 = {lg[4] - lse, lg[5] - lse, lg[6] - lse, lg[7] - lse};
        float4* op = (float4*)(out + (size_t)node * 8);
        op[0] = o0;
        op[1] = o1;
    }
}

extern "C" void kernel_launch(void* const* d_in, const int* in_sizes, int n_in,
                              void* d_out, int out_size, void* d_ws, size_t ws_size,
                              hipStream_t stream) {
    const float* x     = (const float*)d_in[0];
    const int*   ei    = (const int*)d_in[1];
    const float* w_in  = (const float*)d_in[2];
    const float* b_in  = (const float*)d_in[3];
    const float* w1    = (const float*)d_in[4];
    const float* b1    = (const float*)d_in[5];
    const float* w2    = (const float*)d_in[6];
    const float* b2    = (const float*)d_in[7];
    const float* w3    = (const float*)d_in[8];
    const float* b3    = (const float*)d_in[9];
    const float* w_o   = (const float*)d_in[10];
    const float* b_o   = (const float*)d_in[11];
    const float* g1    = (const float*)d_in[12];
    const float* be1   = (const float*)d_in[13];
    const float* m1    = (const float*)d_in[14];
    const float* v1    = (const float*)d_in[15];
    const float* g2    = (const float*)d_in[16];
    const float* be2   = (const float*)d_in[17];
    const float* m2    = (const float*)d_in[18];
    const float* v2    = (const float*)d_in[19];
    const float* g3    = (const float*)d_in[20];
    const float* be3   = (const float*)d_in[21];
    const float* m3    = (const float*)d_in[22];
    const float* v3    = (const float*)d_in[23];

    const int N = in_sizes[0] / 128;
    const int E = in_sizes[1] / 2;
    const int K = (N + (1 << BSH) - 1) >> BSH;

    char* p = (char*)d_ws;
    auto alloc = [&](size_t bytes) {
        void* r = (void*)p;
        p += (bytes + 255) & ~(size_t)255;
        return r;
    };
    int*            cnt  = (int*)alloc((size_t)N * 4);
    float*          dinv = (float*)alloc((size_t)N * 4);
    int*            zbuf = (int*)alloc(512 * 4);         // [0..255]=bcnt, [256..383]=dhist
    int*            doff = (int*)alloc(128 * 4);
    int*            perm = (int*)alloc((size_t)N * 4);
    int*            col  = (int*)alloc((size_t)N * CAP * 4);
    uint2*          bins = (uint2*)alloc((size_t)K * BCAP * 8);
    unsigned short* hbA  = (unsigned short*)alloc((size_t)N * 128 * 2);
    unsigned short* hbB  = (unsigned short*)alloc((size_t)N * 128 * 2);
    unsigned short* f_in = (unsigned short*)alloc(8192 * 2);
    unsigned short* f1   = (unsigned short*)alloc(8192 * 2);
    unsigned short* f2   = (unsigned short*)alloc(16384 * 2);
    unsigned short* f3   = (unsigned short*)alloc(8192 * 2);
    int* bcnt  = zbuf;
    int* dhist = zbuf + 256;

    const int gN  = (N + 255) / 256;
    const int gB1 = (E + 2047) / 2048;
    const int gM  = (N + 63) / 64;

    // graph build + degree sort + weight repack
    k_zero<<<2, 256, 0, stream>>>(zbuf, 512);
    k_bin<<<gB1, 256, 0, stream>>>(ei, E, K, bins, bcnt);
    k_place<<<K, 1024, 0, stream>>>(bins, bcnt, col, cnt, dinv, dhist, N);
    k_prefix<<<1, 64, 0, stream>>>(dhist, doff);
    k_scatter<<<gN, 256, 0, stream>>>(cnt, doff, perm, N);
    k_repack<<<160, 256, 0, stream>>>(w_in, w1, w2, w3, f_in, f1, f2, f3);

    // h0 = bf16( dinv * relu(x @ w_in + b_in) )                     [N,64]  -> hbA
    mfma_gemm0<<<gM, 256, 0, stream>>>(x, f_in, b_in, dinv, hbA, N);
    // h1 = bf16( dinv * relu(bn1( (A_hat@h0) @ w1 + b1 )) )         [N,128] -> hbB
    agg_mfma1<<<gM, 256, 0, stream>>>(hbA, f1, b1, g1, be1, m1, v1, col, cnt, dinv, perm, hbB, N);
    // t3 = bf16( dinv * ( relu(bn2((A_hat@h1)@w2+b2)) @ w3 ) )      [N,64]  -> hbA
    agg_mfma23<<<gM, 256, 0, stream>>>(hbB, f2, b2, g2, be2, m2, v2, f3, col, cnt, dinv, perm, hbA, N);
    // out = log_softmax( relu(bn3(A_hat@t3 + b3)) @ w_out + b_out ) [N,8]
    agg_final<<<gM, 256, 0, stream>>>(hbA, col, cnt, dinv, perm, b3, g3, be3, m3, v3, w_o, b_o, (float*)d_out, N);
}

// Round 9
// 355.793 us; speedup vs baseline: 1.0837x; 1.0837x over previous
//
#include <hip/hip_runtime.h>
#include <math.h>

#define BN_EPS 1e-5f
constexpr int CAP = 64;     // max neighbors/node incl self-loop; deg~Poisson(16), P(>63)~0
constexpr int BSH = 9;      // dst-bucket shift: 512 nodes / bucket
constexpr int BCAP = 10240; // entries per bucket (avg 8192, sd ~90; +22 sigma)

typedef __attribute__((ext_vector_type(8))) short bf16x8;
typedef __attribute__((ext_vector_type(4))) float f32x4;

// ---- bf16 helpers (round-to-nearest-even) ----
__device__ inline unsigned short f2bf(float f) {
    unsigned u = __float_as_uint(f);
    unsigned r = (u + 0x7fffu + ((u >> 16) & 1u)) >> 16;
    return (unsigned short)r;
}
__device__ inline float2 bf2_to_f2(unsigned int v) {
    float2 r;
    r.x = __uint_as_float(v << 16);
    r.y = __uint_as_float(v & 0xffff0000u);
    return r;
}
__device__ inline void addv(float* a, uint4 v) {
    float2 x0 = bf2_to_f2(v.x), x1 = bf2_to_f2(v.y), x2 = bf2_to_f2(v.z), x3 = bf2_to_f2(v.w);
    a[0] += x0.x; a[1] += x0.y; a[2] += x1.x; a[3] += x1.y;
    a[4] += x2.x; a[5] += x2.y; a[6] += x3.x; a[7] += x3.y;
}

// ---------------- graph build: 2-phase dst-binned counting sort ----------------
__global__ __launch_bounds__(256) void k_zero(int* __restrict__ buf, int L) {
    int i = blockIdx.x * 256 + threadIdx.x;
    if (i < L) buf[i] = 0;
}

__global__ __launch_bounds__(256) void k_bin(const int* __restrict__ ei, int E, int K,
                                             uint2* __restrict__ bins, int* __restrict__ bcnt) {
    __shared__ int hist[256];
    __shared__ int lbase[256];
    const int tid = threadIdx.x;
    const int e0 = blockIdx.x * 2048;
    hist[tid] = 0;
    __syncthreads();

    int s[8], d[8];
    bool m[8];
#pragma unroll
    for (int i = 0; i < 8; ++i) {
        int e = e0 + i * 256 + tid;
        m[i] = e < E;
        s[i] = m[i] ? ei[e] : 0;
        d[i] = m[i] ? ei[E + e] : 0;
        if (m[i]) atomicAdd(&hist[d[i] >> BSH], 1);
    }
    __syncthreads();
    if (tid < K && hist[tid] > 0) lbase[tid] = atomicAdd(&bcnt[tid], hist[tid]);
    __syncthreads();
    hist[tid] = 0;
    __syncthreads();
#pragma unroll
    for (int i = 0; i < 8; ++i) {
        if (m[i]) {
            int b = d[i] >> BSH;
            int pos = lbase[b] + atomicAdd(&hist[b], 1);
            if (pos < BCAP) bins[(size_t)b * BCAP + pos] = make_uint2((unsigned)s[i], (unsigned)d[i]);
        }
    }
}

__global__ __launch_bounds__(1024) void k_place(const uint2* __restrict__ bins,
                                                const int* __restrict__ bcnt,
                                                int* __restrict__ col, int* __restrict__ cnt,
                                                float* __restrict__ dinv, int* __restrict__ dhist,
                                                int N) {
    const int b = blockIdx.x;
    const int node0 = b << BSH;
    const int nn = min(1 << BSH, N - node0);
    __shared__ int c2[1 << BSH];
    __shared__ int lh[CAP + 2];
    const int tid = threadIdx.x;
    if (tid < CAP + 2) lh[tid] = 0;
    for (int i = tid; i < nn; i += 1024) {
        c2[i] = 1;
        col[(size_t)(node0 + i) * CAP] = node0 + i;
    }
    __syncthreads();
    const int nb = min(bcnt[b], BCAP);
    const uint2* __restrict__ bb = bins + (size_t)b * BCAP;
    for (int i = tid; i < nb; i += 1024) {
        uint2 e = bb[i];
        int pos = atomicAdd(&c2[(int)e.y - node0], 1);
        if (pos < CAP) col[(size_t)e.y * CAP + pos] = (int)e.x;
    }
    __syncthreads();
    for (int i = tid; i < nn; i += 1024) {
        int c = c2[i];
        cnt[node0 + i] = c;
        dinv[node0 + i] = rsqrtf((float)c);
        atomicAdd(&lh[min(c, CAP)], 1);
    }
    __syncthreads();
    if (tid <= CAP && lh[tid] > 0) atomicAdd(&dhist[tid], lh[tid]);
}

// exclusive prefix over degree histogram, DESCENDING degree -> heavy blocks launch first
__global__ void k_prefix(const int* __restrict__ dhist, int* __restrict__ doff) {
    if (threadIdx.x == 0) {
        int s = 0;
        for (int b = CAP; b >= 0; --b) { doff[b] = s; s += dhist[b]; }
    }
}

// scatter node ids into degree-sorted permutation
__global__ __launch_bounds__(256) void k_scatter(const int* __restrict__ cnt, int* __restrict__ doff,
                                                 int* __restrict__ perm, int N) {
    __shared__ int lh[CAP + 2];
    __shared__ int lbase[CAP + 2];
    __shared__ int lpos[CAP + 2];
    const int tid = threadIdx.x;
    if (tid < CAP + 2) { lh[tid] = 0; lpos[tid] = 0; }
    __syncthreads();
    const int i = blockIdx.x * 256 + tid;
    const bool act = i < N;
    int b = 0;
    if (act) { b = min(cnt[i], CAP); atomicAdd(&lh[b], 1); }
    __syncthreads();
    if (tid <= CAP && lh[tid] > 0) lbase[tid] = atomicAdd(&doff[tid], lh[tid]);
    __syncthreads();
    if (act) {
        int p = atomicAdd(&lpos[b], 1);
        perm[lbase[b] + p] = i;
    }
}

// ---------------- weight repack: fp32 [FIN][FOUT] -> bf16 fragment-linear ----------------
__global__ __launch_bounds__(256) void k_repack(
    const float* __restrict__ w_in, const float* __restrict__ w1,
    const float* __restrict__ w2, const float* __restrict__ w3,
    unsigned short* __restrict__ f_in, unsigned short* __restrict__ f1,
    unsigned short* __restrict__ f2, unsigned short* __restrict__ f3)
{
    int idx = blockIdx.x * 256 + threadIdx.x;  // 0..40959
    const float* src;
    unsigned short* dst;
    int FOUT, local;
    if (idx < 8192)       { src = w_in; dst = f_in; FOUT = 64;  local = idx; }
    else if (idx < 16384) { src = w1;   dst = f1;   FOUT = 128; local = idx - 8192; }
    else if (idx < 32768) { src = w2;   dst = f2;   FOUT = 128; local = idx - 16384; }
    else                  { src = w3;   dst = f3;   FOUT = 64;  local = idx - 32768; }
    int k = local / FOUT, n = local % FOUT;
    int NT = FOUT >> 4;
    dst[((((k >> 5) * NT + (n >> 4)) * 64) + ((k >> 3) & 3) * 16 + (n & 15)) * 8 + (k & 7)] = f2bf(src[local]);
}

// ---------------- layer 0: h0 = bf16( dinv * relu(x @ w_in + b_in) ) ----------------
__global__ __launch_bounds__(256) void mfma_gemm0(
    const float* __restrict__ in, const unsigned short* __restrict__ wfrag,
    const float* __restrict__ bias, const float* __restrict__ rowscale,
    unsigned short* __restrict__ out, int N)
{
    constexpr int FIN = 128, FOUT = 64, KS = 4, NT = 4, OST = 72;
    __shared__ unsigned short otile[4 * 16 * OST];
    __shared__ float ct[FOUT];
    const int tid = threadIdx.x;
    if (tid < FOUT) ct[tid] = bias[tid];
    __syncthreads();

    const int wid = tid >> 6, lane = tid & 63;
    const int q = lane >> 4, m = lane & 15;
    const int rowbase = blockIdx.x * 64 + wid * 16;
    const int rowc = min(rowbase + m, N - 1);
    const bf16x8* __restrict__ wf = (const bf16x8*)wfrag;

    f32x4 accm[NT];
#pragma unroll
    for (int nt = 0; nt < NT; ++nt) accm[nt] = (f32x4){0.f, 0.f, 0.f, 0.f};

#pragma unroll
    for (int ks = 0; ks < KS; ++ks) {
        const float* ap = in + (size_t)rowc * FIN + ks * 32 + q * 8;
        float4 a0 = *(const float4*)ap;
        float4 a1 = *(const float4*)(ap + 4);
        bf16x8 af;
        af[0] = (short)f2bf(a0.x); af[1] = (short)f2bf(a0.y);
        af[2] = (short)f2bf(a0.z); af[3] = (short)f2bf(a0.w);
        af[4] = (short)f2bf(a1.x); af[5] = (short)f2bf(a1.y);
        af[6] = (short)f2bf(a1.z); af[7] = (short)f2bf(a1.w);
#pragma unroll
        for (int nt = 0; nt < NT; ++nt)
            accm[nt] = __builtin_amdgcn_mfma_f32_16x16x32_bf16(af, wf[(ks * NT + nt) * 64 + lane], accm[nt], 0, 0, 0);
    }

    unsigned short* ot = otile + wid * 16 * OST;
    float rs[4];
#pragma unroll
    for (int r = 0; r < 4; ++r) rs[r] = rowscale[min(rowbase + q * 4 + r, N - 1)];
#pragma unroll
    for (int nt = 0; nt < NT; ++nt) {
        int c = nt * 16 + m;
        float t = ct[c];
#pragma unroll
        for (int r = 0; r < 4; ++r) {
            float z = fmaxf(accm[nt][r] + t, 0.f);
            ot[(q * 4 + r) * OST + c] = f2bf(z * rs[r]);
        }
    }
#pragma unroll
    for (int idx = lane; idx < 16 * (FOUT / 8); idx += 64) {
        int rrow = idx >> 3, cc = idx & 7;
        int gr = rowbase + rrow;
        if (gr < N)
            *(uint4*)(out + (size_t)gr * FOUT + cc * 8) = *(const uint4*)&ot[rrow * OST + cc * 8];
    }
}

// ---------------- layer 1: h1 = bf16( dinv * relu(bn1( (A_hat@h0) @ w1 + b1 )) ) ----------------
// Gather-in-fragment, degree-equalized, 8-neighbor batches (16 uint4 in flight).
__global__ __launch_bounds__(256) void agg_mfma1(
    const unsigned short* __restrict__ hin, const unsigned short* __restrict__ wfrag,
    const float* __restrict__ bias, const float* __restrict__ g, const float* __restrict__ beta,
    const float* __restrict__ mm, const float* __restrict__ vv,
    const int* __restrict__ col, const int* __restrict__ cnt, const float* __restrict__ dinv,
    const int* __restrict__ perm,
    unsigned short* __restrict__ out, int N)
{
    constexpr int FIN = 64, FOUT = 128, KS = 2, NT = 8, OST = 136;
    __shared__ unsigned short otile[4 * 16 * OST];
    __shared__ float cs[FOUT], ct[FOUT];
    __shared__ int lperm[64];
    const int tid = threadIdx.x;
    if (tid < FOUT) {
        float s = g[tid] * rsqrtf(vv[tid] + BN_EPS);
        cs[tid] = s;
        ct[tid] = bias[tid] * s + beta[tid] - mm[tid] * s;
    }
    if (tid < 64) lperm[tid] = perm[min((int)(blockIdx.x * 64 + tid), N - 1)];
    __syncthreads();

    const int wid = tid >> 6, lane = tid & 63;
    const int q = lane >> 4, m = lane & 15;
    const int rowbase = blockIdx.x * 64 + wid * 16;
    const int node = lperm[wid * 16 + m];
    const int n = (rowbase + m < N) ? min(cnt[node], CAP) : 0;
    const int* __restrict__ c = col + (size_t)node * CAP;

    float acc[KS][8];
#pragma unroll
    for (int i = 0; i < KS; ++i)
#pragma unroll
        for (int e = 0; e < 8; ++e) acc[i][e] = 0.f;

    int p = 0;
    for (; p + 8 <= n; p += 8) {
        int4 ca = *(const int4*)(c + p);
        int4 cb = *(const int4*)(c + p + 4);
        const unsigned short* r0 = hin + (size_t)ca.x * FIN + q * 8;
        const unsigned short* r1 = hin + (size_t)ca.y * FIN + q * 8;
        const unsigned short* r2 = hin + (size_t)ca.z * FIN + q * 8;
        const unsigned short* r3 = hin + (size_t)ca.w * FIN + q * 8;
        const unsigned short* r4 = hin + (size_t)cb.x * FIN + q * 8;
        const unsigned short* r5 = hin + (size_t)cb.y * FIN + q * 8;
        const unsigned short* r6 = hin + (size_t)cb.z * FIN + q * 8;
        const unsigned short* r7 = hin + (size_t)cb.w * FIN + q * 8;
        uint4 v0a = *(const uint4*)r0, v0b = *(const uint4*)(r0 + 32);
        uint4 v1a = *(const uint4*)r1, v1b = *(const uint4*)(r1 + 32);
        uint4 v2a = *(const uint4*)r2, v2b = *(const uint4*)(r2 + 32);
        uint4 v3a = *(const uint4*)r3, v3b = *(const uint4*)(r3 + 32);
        uint4 v4a = *(const uint4*)r4, v4b = *(const uint4*)(r4 + 32);
        uint4 v5a = *(const uint4*)r5, v5b = *(const uint4*)(r5 + 32);
        uint4 v6a = *(const uint4*)r6, v6b = *(const uint4*)(r6 + 32);
        uint4 v7a = *(const uint4*)r7, v7b = *(const uint4*)(r7 + 32);
        addv(acc[0], v0a); addv(acc[1], v0b);
        addv(acc[0], v1a); addv(acc[1], v1b);
        addv(acc[0], v2a); addv(acc[1], v2b);
        addv(acc[0], v3a); addv(acc[1], v3b);
        addv(acc[0], v4a); addv(acc[1], v4b);
        addv(acc[0], v5a); addv(acc[1], v5b);
        addv(acc[0], v6a); addv(acc[1], v6b);
        addv(acc[0], v7a); addv(acc[1], v7b);
    }
    for (; p + 4 <= n; p += 4) {
        int4 ca = *(const int4*)(c + p);
        const unsigned short* r0 = hin + (size_t)ca.x * FIN + q * 8;
        const unsigned short* r1 = hin + (size_t)ca.y * FIN + q * 8;
        const unsigned short* r2 = hin + (size_t)ca.z * FIN + q * 8;
        const unsigned short* r3 = hin + (size_t)ca.w * FIN + q * 8;
        uint4 v0a = *(const uint4*)r0, v0b = *(const uint4*)(r0 + 32);
        uint4 v1a = *(const uint4*)r1, v1b = *(const uint4*)(r1 + 32);
        uint4 v2a = *(const uint4*)r2, v2b = *(const uint4*)(r2 + 32);
        uint4 v3a = *(const uint4*)r3, v3b = *(const uint4*)(r3 + 32);
        addv(acc[0], v0a); addv(acc[1], v0b);
        addv(acc[0], v1a); addv(acc[1], v1b);
        addv(acc[0], v2a); addv(acc[1], v2b);
        addv(acc[0], v3a); addv(acc[1], v3b);
    }
    for (; p < n; ++p) {
        const unsigned short* r0 = hin + (size_t)c[p] * FIN + q * 8;
        addv(acc[0], *(const uint4*)r0);
        addv(acc[1], *(const uint4*)(r0 + 32));
    }

    const float di = dinv[node];
    bf16x8 af[KS];
#pragma unroll
    for (int i = 0; i < KS; ++i)
#pragma unroll
        for (int e = 0; e < 8; ++e) af[i][e] = (short)f2bf(acc[i][e] * di);

    f32x4 accm[NT];
#pragma unroll
    for (int nt = 0; nt < NT; ++nt) accm[nt] = (f32x4){0.f, 0.f, 0.f, 0.f};
    const bf16x8* __restrict__ wf = (const bf16x8*)wfrag;
#pragma unroll
    for (int ks = 0; ks < KS; ++ks)
#pragma unroll
        for (int nt = 0; nt < NT; ++nt)
            accm[nt] = __builtin_amdgcn_mfma_f32_16x16x32_bf16(af[ks], wf[(ks * NT + nt) * 64 + lane], accm[nt], 0, 0, 0);

    unsigned short* ot = otile + wid * 16 * OST;
    float rs[4];
#pragma unroll
    for (int r = 0; r < 4; ++r) rs[r] = dinv[lperm[wid * 16 + q * 4 + r]];
#pragma unroll
    for (int nt = 0; nt < NT; ++nt) {
        int cc = nt * 16 + m;
        float s = cs[cc], t = ct[cc];
#pragma unroll
        for (int r = 0; r < 4; ++r) {
            float z = fmaxf(accm[nt][r] * s + t, 0.f);
            ot[(q * 4 + r) * OST + cc] = f2bf(z * rs[r]);
        }
    }
#pragma unroll
    for (int idx = lane; idx < 16 * (FOUT / 8); idx += 64) {
        int rrow = idx >> 4, cc = idx & 15;
        if (rowbase + rrow < N) {
            int gr = lperm[wid * 16 + rrow];
            *(uint4*)(out + (size_t)gr * FOUT + cc * 8) = *(const uint4*)&ot[rrow * OST + cc * 8];
        }
    }
}

// ---------------- layers 2+3 fused: t3 = bf16( dinv * ( relu(bn2((A_hat@h1)@w2+b2)) @ w3 ) ) ----------------
// 4-neighbor gather batches (16 uint4 in flight).
__global__ __launch_bounds__(256) void agg_mfma23(
    const unsigned short* __restrict__ hin, const unsigned short* __restrict__ w2f,
    const float* __restrict__ b2, const float* __restrict__ g2, const float* __restrict__ beta2,
    const float* __restrict__ m2, const float* __restrict__ v2,
    const unsigned short* __restrict__ w3f,
    const int* __restrict__ col, const int* __restrict__ cnt, const float* __restrict__ dinv,
    const int* __restrict__ perm,
    unsigned short* __restrict__ out, int N)
{
    constexpr int FIN = 128, KS = 4, NT1 = 8, NT2 = 4, OST = 136, OST2 = 72;
    __shared__ unsigned short otile[4 * 16 * OST];
    __shared__ float cs[128], ct[128];
    __shared__ int lperm[64];
    const int tid = threadIdx.x;
    if (tid < 128) {
        float s = g2[tid] * rsqrtf(v2[tid] + BN_EPS);
        cs[tid] = s;
        ct[tid] = b2[tid] * s + beta2[tid] - m2[tid] * s;
    }
    if (tid < 64) lperm[tid] = perm[min((int)(blockIdx.x * 64 + tid), N - 1)];
    __syncthreads();

    const int wid = tid >> 6, lane = tid & 63;
    const int q = lane >> 4, m = lane & 15;
    const int rowbase = blockIdx.x * 64 + wid * 16;
    const int node = lperm[wid * 16 + m];
    const int n = (rowbase + m < N) ? min(cnt[node], CAP) : 0;
    const int* __restrict__ c = col + (size_t)node * CAP;

    float acc[KS][8];
#pragma unroll
    for (int i = 0; i < KS; ++i)
#pragma unroll
        for (int e = 0; e < 8; ++e) acc[i][e] = 0.f;

    int p = 0;
    for (; p + 4 <= n; p += 4) {
        int4 ca = *(const int4*)(c + p);
        const unsigned short* r0 = hin + (size_t)ca.x * FIN + q * 8;
        const unsigned short* r1 = hin + (size_t)ca.y * FIN + q * 8;
        const unsigned short* r2 = hin + (size_t)ca.z * FIN + q * 8;
        const unsigned short* r3 = hin + (size_t)ca.w * FIN + q * 8;
        uint4 v0[KS], v1[KS], v2[KS], v3[KS];
#pragma unroll
        for (int i = 0; i < KS; ++i) v0[i] = *(const uint4*)(r0 + i * 32);
#pragma unroll
        for (int i = 0; i < KS; ++i) v1[i] = *(const uint4*)(r1 + i * 32);
#pragma unroll
        for (int i = 0; i < KS; ++i) v2[i] = *(const uint4*)(r2 + i * 32);
#pragma unroll
        for (int i = 0; i < KS; ++i) v3[i] = *(const uint4*)(r3 + i * 32);
#pragma unroll
        for (int i = 0; i < KS; ++i) addv(acc[i], v0[i]);
#pragma unroll
        for (int i = 0; i < KS; ++i) addv(acc[i], v1[i]);
#pragma unroll
        for (int i = 0; i < KS; ++i) addv(acc[i], v2[i]);
#pragma unroll
        for (int i = 0; i < KS; ++i) addv(acc[i], v3[i]);
    }
    for (; p < n; ++p) {
        const unsigned short* r0 = hin + (size_t)c[p] * FIN + q * 8;
#pragma unroll
        for (int i = 0; i < KS; ++i) addv(acc[i], *(const uint4*)(r0 + i * 32));
    }

    const float di = dinv[node];
    bf16x8 af[KS];
#pragma unroll
    for (int i = 0; i < KS; ++i)
#pragma unroll
        for (int e = 0; e < 8; ++e) af[i][e] = (short)f2bf(acc[i][e] * di);

    // MFMA1: z2 = a2 @ w2
    f32x4 accm[NT1];
#pragma unroll
    for (int nt = 0; nt < NT1; ++nt) accm[nt] = (f32x4){0.f, 0.f, 0.f, 0.f};
    const bf16x8* __restrict__ wf2 = (const bf16x8*)w2f;
#pragma unroll
    for (int ks = 0; ks < KS; ++ks)
#pragma unroll
        for (int nt = 0; nt < NT1; ++nt)
            accm[nt] = __builtin_amdgcn_mfma_f32_16x16x32_bf16(af[ks], wf2[(ks * NT1 + nt) * 64 + lane], accm[nt], 0, 0, 0);

    // h2 = relu(bn2(z2)) -> per-wave LDS tile (C-layout rows -> A-frag reads)
    unsigned short* ot = otile + wid * 16 * OST;
#pragma unroll
    for (int nt = 0; nt < NT1; ++nt) {
        int cc = nt * 16 + m;
        float s = cs[cc], t = ct[cc];
#pragma unroll
        for (int r = 0; r < 4; ++r) {
            float z = fmaxf(accm[nt][r] * s + t, 0.f);
            ot[(q * 4 + r) * OST + cc] = f2bf(z);
        }
    }
    bf16x8 af2[KS];
#pragma unroll
    for (int ks = 0; ks < KS; ++ks)
        af2[ks] = *(const bf16x8*)&ot[m * OST + ks * 32 + q * 8];

    // MFMA2: t3 = h2 @ w3
    f32x4 acc2[NT2];
#pragma unroll
    for (int nt = 0; nt < NT2; ++nt) acc2[nt] = (f32x4){0.f, 0.f, 0.f, 0.f};
    const bf16x8* __restrict__ wf3 = (const bf16x8*)w3f;
#pragma unroll
    for (int ks = 0; ks < KS; ++ks)
#pragma unroll
        for (int nt = 0; nt < NT2; ++nt)
            acc2[nt] = __builtin_amdgcn_mfma_f32_16x16x32_bf16(af2[ks], wf3[(ks * NT2 + nt) * 64 + lane], acc2[nt], 0, 0, 0);

    float rs[4];
#pragma unroll
    for (int r = 0; r < 4; ++r) rs[r] = dinv[lperm[wid * 16 + q * 4 + r]];
#pragma unroll
    for (int nt = 0; nt < NT2; ++nt) {
        int cc = nt * 16 + m;
#pragma unroll
        for (int r = 0; r < 4; ++r)
            ot[(q * 4 + r) * OST2 + cc] = f2bf(acc2[nt][r] * rs[r]);
    }
#pragma unroll
    for (int idx = lane; idx < 16 * 8; idx += 64) {
        int rrow = idx >> 3, cc = idx & 7;
        if (rowbase + rrow < N) {
            int gr = lperm[wid * 16 + rrow];
            *(uint4*)(out + (size_t)gr * 64 + cc * 8) = *(const uint4*)&ot[rrow * OST2 + cc * 8];
        }
    }
}

// ---------------- layer 3 tail fused: out = log_softmax( relu(bn3(A_hat@t3 + b3)) @ w_out + b_out ) ----------------
__global__ __launch_bounds__(256) void agg_final(
    const unsigned short* __restrict__ hin,
    const int* __restrict__ col, const int* __restrict__ cnt, const float* __restrict__ dinv,
    const int* __restrict__ perm,
    const float* __restrict__ b3, const float* __restrict__ g3, const float* __restrict__ beta3,
    const float* __restrict__ m3, const float* __restrict__ v3,
    const float* __restrict__ w_out, const float* __restrict__ b_out,
    float* __restrict__ out, int N)
{
    __shared__ float S[64], T[64], sw[64 * 8], sb[8];
    __shared__ int lperm[64];
    const int tid = threadIdx.x;
    if (tid < 64) {
        float s = g3[tid] * rsqrtf(v3[tid] + BN_EPS);
        S[tid] = s;
        T[tid] = b3[tid] * s + beta3[tid] - m3[tid] * s;
        lperm[tid] = perm[min((int)(blockIdx.x * 64 + tid), N - 1)];
    }
    if (tid < 8) sb[tid] = b_out[tid];
    sw[tid] = w_out[tid];
    sw[tid + 256] = w_out[tid + 256];
    __syncthreads();

    const int wid = tid >> 6, lane = tid & 63;
    const int q = lane >> 4, m = lane & 15;
    const int rowbase = blockIdx.x * 64 + wid * 16;
    const int node = lperm[wid * 16 + m];
    const int n = (rowbase + m < N) ? min(cnt[node], CAP) : 0;
    const int* __restrict__ c = col + (size_t)node * CAP;

    float acc[2][8];
#pragma unroll
    for (int i = 0; i < 2; ++i)
#pragma unroll
        for (int e = 0; e < 8; ++e) acc[i][e] = 0.f;

    int p = 0;
    for (; p + 8 <= n; p += 8) {
        int4 ca = *(const int4*)(c + p);
        int4 cb = *(const int4*)(c + p + 4);
        const unsigned short* r0 = hin + (size_t)ca.x * 64 + q * 8;
        const unsigned short* r1 = hin + (size_t)ca.y * 64 + q * 8;
        const unsigned short* r2 = hin + (size_t)ca.z * 64 + q * 8;
        const unsigned short* r3 = hin + (size_t)ca.w * 64 + q * 8;
        const unsigned short* r4 = hin + (size_t)cb.x * 64 + q * 8;
        const unsigned short* r5 = hin + (size_t)cb.y * 64 + q * 8;
        const unsigned short* r6 = hin + (size_t)cb.z * 64 + q * 8;
        const unsigned short* r7 = hin + (size_t)cb.w * 64 + q * 8;
        uint4 v0a = *(const uint4*)r0, v0b = *(const uint4*)(r0 + 32);
        uint4 v1a = *(const uint4*)r1, v1b = *(const uint4*)(r1 + 32);
        uint4 v2a = *(const uint4*)r2, v2b = *(const uint4*)(r2 + 32);
        uint4 v3a = *(const uint4*)r3, v3b = *(const uint4*)(r3 + 32);
        uint4 v4a = *(const uint4*)r4, v4b = *(const uint4*)(r4 + 32);
        uint4 v5a = *(const uint4*)r5, v5b = *(const uint4*)(r5 + 32);
        uint4 v6a = *(const uint4*)r6, v6b = *(const uint4*)(r6 + 32);
        uint4 v7a = *(const uint4*)r7, v7b = *(const uint4*)(r7 + 32);
        addv(acc[0], v0a); addv(acc[1], v0b);
        addv(acc[0], v1a); addv(acc[1], v1b);
        addv(acc[0], v2a); addv(acc[1], v2b);
        addv(acc[0], v3a); addv(acc[1], v3b);
        addv(acc[0], v4a); addv(acc[1], v4b);
        addv(acc[0], v5a); addv(acc[1], v5b);
        addv(acc[0], v6a); addv(acc[1], v6b);
        addv(acc[0], v7a); addv(acc[1], v7b);
    }
    for (; p + 4 <= n; p += 4) {
        int4 ca = *(const int4*)(c + p);
        const unsigned short* r0 = hin + (size_t)ca.x * 64 + q * 8;
        const unsigned short* r1 = hin + (size_t)ca.y * 64 + q * 8;
        const unsigned short* r2 = hin + (size_t)ca.z * 64 + q * 8;
        const unsigned short* r3 = hin + (size_t)ca.w * 64 + q * 8;
        uint4 v0a = *(const uint4*)r0, v0b = *(const uint4*)(r0 + 32);
        uint4 v1a = *(const uint4*)r1, v1b = *(const uint4*)(r1 + 32);
        uint4 v2a = *(const uint4*)r2, v2b = *(const uint4*)(r2 + 32);
        uint4 v3a = *(const uint4*)r3, v3b = *(const uint4*)(r3 + 32);
        addv(acc[0], v0a); addv(acc[1], v0b);
        addv(acc[0], v1a); addv(acc[1], v1b);
        addv(acc[0], v2a); addv(acc[1], v2b);
        addv(acc[0], v3a); addv(acc[1], v3b);
    }
    for (; p < n; ++p) {
        const unsigned short* r0 = hin + (size_t)c[p] * 64 + q * 8;
        addv(acc[0], *(const uint4*)r0);
        addv(acc[1], *(const uint4*)(r0 + 32));
    }

    const float di = dinv[node];
    float lg[8];
#pragma unroll
    for (int cc = 0; cc < 8; ++cc) lg[cc] = 0.f;
#pragma unroll
    for (int i = 0; i < 2; ++i) {
        int fbase = i * 32 + q * 8;
#pragma unroll
        for (int j = 0; j < 8; ++j) {
            int f = fbase + j;
            float z = fmaxf((acc[i][j] * di) * S[f] + T[f], 0.f);
#pragma unroll
            for (int cc = 0; cc < 8; ++cc) lg[cc] += z * sw[f * 8 + cc];
        }
    }
#pragma unroll
    for (int cc = 0; cc < 8; ++cc) {
        lg[cc] += __shfl_xor(lg[cc], 16);
        lg[cc] += __shfl_xor(lg[cc], 32);
    }
    if (q == 0 && rowbase + m < N) {
#pragma unroll
        for (int cc = 0; cc < 8; ++cc) lg[cc] += sb[cc];
        float mx = lg[0];
#pragma unroll
        for (int cc = 1; cc < 8; ++cc) mx = fmaxf(mx, lg[cc]);
        float sum = 0.f;
#pragma unroll
        for (int cc = 0; cc < 8; ++cc) sum += expf(lg[cc] - mx);
        float lse = logf(sum) + mx;
        float4 o0 = {lg[0] - lse, lg[1] - lse, lg[2] - lse, lg[3] - lse};
        float4 o1 = {lg[4] - lse, lg[5] - lse, lg[6] - lse, lg[7] - lse};
        float4* op = (float4*)(out + (size_t)node * 8);
        op[0] = o0;
        op[1] = o1;
    }
}

extern "C" void kernel_launch(void* const* d_in, const int* in_sizes, int n_in,
                              void* d_out, int out_size, void* d_ws, size_t ws_size,
                              hipStream_t stream) {
    const float* x     = (const float*)d_in[0];
    const int*   ei    = (const int*)d_in[1];
    const float* w_in  = (const float*)d_in[2];
    const float* b_in  = (const float*)d_in[3];
    const float* w1    = (const float*)d_in[4];
    const float* b1    = (const float*)d_in[5];
    const float* w2    = (const float*)d_in[6];
    const float* b2    = (const float*)d_in[7];
    const float* w3    = (const float*)d_in[8];
    const float* b3    = (const float*)d_in[9];
    const float* w_o   = (const float*)d_in[10];
    const float* b_o   = (const float*)d_in[11];
    const float* g1    = (const float*)d_in[12];
    const float* be1   = (const float*)d_in[13];
    const float* m1    = (const float*)d_in[14];
    const float* v1    = (const float*)d_in[15];
    const float* g2    = (const float*)d_in[16];
    const float* be2   = (const float*)d_in[17];
    const float* m2    = (const float*)d_in[18];
    const float* v2    = (const float*)d_in[19];
    const float* g3    = (const float*)d_in[20];
    const float* be3   = (const float*)d_in[21];
    const float* m3    = (const float*)d_in[22];
    const float* v3    = (const float*)d_in[23];

    const int N = in_sizes[0] / 128;
    const int E = in_sizes[1] / 2;
    const int K = (N + (1 << BSH) - 1) >> BSH;

    char* p = (char*)d_ws;
    auto alloc = [&](size_t bytes) {
        void* r = (void*)p;
        p += (bytes + 255) & ~(size_t)255;
        return r;
    };
    int*            cnt  = (int*)alloc((size_t)N * 4);
    float*          dinv = (float*)alloc((size_t)N * 4);
    int*            zbuf = (int*)alloc(512 * 4);         // [0..255]=bcnt, [256..383]=dhist
    int*            doff = (int*)alloc(128 * 4);
    int*            perm = (int*)alloc((size_t)N * 4);
    int*            col  = (int*)alloc((size_t)N * CAP * 4);
    uint2*          bins = (uint2*)alloc((size_t)K * BCAP * 8);
    unsigned short* hbA  = (unsigned short*)alloc((size_t)N * 128 * 2);
    unsigned short* hbB  = (unsigned short*)alloc((size_t)N * 128 * 2);
    unsigned short* f_in = (unsigned short*)alloc(8192 * 2);
    unsigned short* f1   = (unsigned short*)alloc(8192 * 2);
    unsigned short* f2   = (unsigned short*)alloc(16384 * 2);
    unsigned short* f3   = (unsigned short*)alloc(8192 * 2);
    int* bcnt  = zbuf;
    int* dhist = zbuf + 256;

    const int gN  = (N + 255) / 256;
    const int gB1 = (E + 2047) / 2048;
    const int gM  = (N + 63) / 64;

    // graph build + degree sort (descending) + weight repack
    k_zero<<<2, 256, 0, stream>>>(zbuf, 512);
    k_bin<<<gB1, 256, 0, stream>>>(ei, E, K, bins, bcnt);
    k_place<<<K, 1024, 0, stream>>>(bins, bcnt, col, cnt, dinv, dhist, N);
    k_prefix<<<1, 64, 0, stream>>>(dhist, doff);
    k_scatter<<<gN, 256, 0, stream>>>(cnt, doff, perm, N);
    k_repack<<<160, 256, 0, stream>>>(w_in, w1, w2, w3, f_in, f1, f2, f3);

    // h0 = bf16( dinv * relu(x @ w_in + b_in) )                     [N,64]  -> hbA
    mfma_gemm0<<<gM, 256, 0, stream>>>(x, f_in, b_in, dinv, hbA, N);
    // h1 = bf16( dinv * relu(bn1( (A_hat@h0) @ w1 + b1 )) )         [N,128] -> hbB
    agg_mfma1<<<gM, 256, 0, stream>>>(hbA, f1, b1, g1, be1, m1, v1, col, cnt, dinv, perm, hbB, N);
    // t3 = bf16( dinv * ( relu(bn2((A_hat@h1)@w2+b2)) @ w3 ) )      [N,64]  -> hbA
    agg_mfma23<<<gM, 256, 0, stream>>>(hbB, f2, b2, g2, be2, m2, v2, f3, col, cnt, dinv, perm, hbA, N);
    // out = log_softmax( relu(bn3(A_hat@t3 + b3)) @ w_out + b_out ) [N,8]
    agg_final<<<gM, 256, 0, stream>>>(hbA, col, cnt, dinv, perm, b3, g3, be3, m3, v3, w_o, b_o, (float*)d_out, N);
}